// Round 1
// baseline (170.049 us; speedup 1.0000x reference)
//
#include <hip/hip_runtime.h>
#include <math.h>

#define SDF_W      7000.0f
#define EIK_W      600.0f
#define ORI_W      500.0f
#define NEAR_ORI_W 10.0f
#define GRADN_W    200.0f

#define TILE   2048          // points per LDS tile (32 KB of float4)
#define NWAVE  8             // 512-thread blocks
#define CHK    64            // chunk granularity for index recovery
#define QPL    4             // queries per lane in nn_scan
#define QB     (QPL * 64)    // queries per block = 256
#define WS_STRIDE 8192       // per-array stride (floats) for block partials
#define WS_REC 65536         // float offset of per-query records

// ws float layout:
//   [k*8192 .. k*8192+RB) : recover-block partials, k = 0:ori 1:nori 2:sdf 3:eik 4:gn
//   [65536 ...)           : records, float4 per (query, S-half): {M1, M2, c1, c2}

__device__ __forceinline__ float neg_half_norm2(float sx, float sy, float sz) {
    return -0.5f * fmaf(sx, sx, fmaf(sy, sy, sz * sz));
}
// Deterministic score; must be bit-identical between nn_scan and recover_k.
__device__ __forceinline__ float score(float qx, float qy, float qz,
                                       float sx, float sy, float sz, float nh) {
    return fmaf(qx, sx, fmaf(qy, sy, fmaf(qz, sz, nh)));
}

__device__ __forceinline__ float dot_at(const float* __restrict__ surf,
                                        const float* __restrict__ norms, int j,
                                        float qx, float qy, float qz) {
    float sx = surf[3*j], sy = surf[3*j+1], sz = surf[3*j+2];
    float nx = norms[3*j], ny = norms[3*j+1], nz = norms[3*j+2];
    return fmaf(qx - sx, nx, fmaf(qy - sy, ny, (qz - sz) * nz));
}

// ---------------------------------------------------------------------------
// Hot kernel: top-2 score values per (query, S-half) with chunk ids.
// 4 queries per lane amortize each broadcast ds_read_b128 over 256 evals/wave.
// M2 update via single v_med3_f32: med3(g, M1, M2) == max(M2, min(g, M1)).
// ---------------------------------------------------------------------------
__global__ __launch_bounds__(512) void nn_scan(
    const float* __restrict__ offq, const float* __restrict__ nearq,
    const float* __restrict__ surf,
    float* __restrict__ ws, int S, int Qoff, int QT)
{
    __shared__ float4 tile[TILE];                 // 32 KB; reused for merge recs
    const int t    = threadIdx.x;
    const int lane = t & 63;
    const int wv   = __builtin_amdgcn_readfirstlane(t >> 6);   // 0..7

    const int qgroup = blockIdx.x >> 1;
    const int shalf  = blockIdx.x & 1;

    const int halfLen = (((S + 1) / 2) + (CHK - 1)) & ~(CHK - 1);
    const int sb = shalf ? (halfLen < S ? halfLen : S) : 0;
    const int se = shalf ? S : (halfLen < S ? halfLen : S);

    // four queries per lane
    const int qbase = qgroup * QB;
    float qx[QPL], qy[QPL], qz[QPL];
    #pragma unroll
    for (int j = 0; j < QPL; ++j) {
        int q = qbase + j * 64 + lane;
        qx[j] = 0.f; qy[j] = 0.f; qz[j] = 0.f;
        if (q < QT) {
            const float* p = (q < Qoff) ? (offq + 3 * q) : (nearq + 3 * (q - Qoff));
            qx[j] = p[0]; qy[j] = p[1]; qz[j] = p[2];
        }
    }

    float M1[QPL], M2[QPL], P1[QPL], P2[QPL];
    int c1[QPL], c2[QPL];
    #pragma unroll
    for (int j = 0; j < QPL; ++j) {
        M1[j] = -3.0e38f; M2[j] = -3.0e38f;
        P1[j] = -3.0e38f; P2[j] = -3.0e38f;
        c1[j] = 0; c2[j] = 0;
    }

    for (int base = sb; base < se; base += TILE) {
        __syncthreads();
        // ---- stage 2048 points (4 per thread) as (x,y,z,-|s|^2/2) ----
        {
            int p0 = base + t * 4;
            if (p0 + 4 <= se) {
                const float4* g4 = (const float4*)(surf + 3 * p0);   // 48B aligned
                float4 r0 = g4[0], r1 = g4[1], r2 = g4[2];
                tile[t*4+0] = make_float4(r0.x, r0.y, r0.z, neg_half_norm2(r0.x, r0.y, r0.z));
                tile[t*4+1] = make_float4(r0.w, r1.x, r1.y, neg_half_norm2(r0.w, r1.x, r1.y));
                tile[t*4+2] = make_float4(r1.z, r1.w, r2.x, neg_half_norm2(r1.z, r1.w, r2.x));
                tile[t*4+3] = make_float4(r2.y, r2.z, r2.w, neg_half_norm2(r2.y, r2.z, r2.w));
            } else {
                #pragma unroll
                for (int k = 0; k < 4; ++k) {
                    int p = p0 + k;
                    if (p < se) {
                        float sx = surf[3*p], sy = surf[3*p+1], sz = surf[3*p+2];
                        tile[t*4+k] = make_float4(sx, sy, sz, neg_half_norm2(sx, sy, sz));
                    } else {
                        tile[t*4+k] = make_float4(0.f, 0.f, 0.f, -3.0e38f);
                    }
                }
            }
        }
        __syncthreads();
        // ---- scan: wave wv covers 256 pts = 4 chunks of 64 ----
        const int lo = wv * (TILE / NWAVE);
        const float4* tp = tile + lo;
        const int ccbase = (base + lo) >> 6;                  // wave-uniform
        #pragma unroll 1
        for (int c4 = 0; c4 < (TILE / NWAVE) / CHK; ++c4) {
            const float4* cp = tp + c4 * CHK;
            #pragma unroll 8
            for (int o = 0; o < CHK; ++o) {
                float4 s4 = cp[o];                            // broadcast b128
                #pragma unroll
                for (int j = 0; j < QPL; ++j) {
                    float g = score(qx[j], qy[j], qz[j], s4.x, s4.y, s4.z, s4.w);
                    M2[j] = __builtin_amdgcn_fmed3f(g, M1[j], M2[j]);  // uses OLD M1
                    M1[j] = fmaxf(M1[j], g);
                }
            }
            int cid = ccbase + c4;
            #pragma unroll
            for (int j = 0; j < QPL; ++j) {
                c1[j] = (M1[j] != P1[j]) ? cid : c1[j];  P1[j] = M1[j];
                c2[j] = (M2[j] != P2[j]) ? cid : c2[j];  P2[j] = M2[j];
            }
        }
    }

    // ---- merge 8 wave-partials per query, write record to ws ----
    __syncthreads();
    float4* rec = tile;                                       // reuse LDS (2048 slots)
    #pragma unroll
    for (int j = 0; j < QPL; ++j)
        rec[wv * QB + j * 64 + lane] =
            make_float4(M1[j], M2[j], __int_as_float(c1[j]), __int_as_float(c2[j]));
    __syncthreads();
    if (t < QB) {
        float4 r = rec[t];
        float m1 = r.x, m2 = r.y;
        int k1 = __float_as_int(r.z), k2 = __float_as_int(r.w);
        #pragma unroll
        for (int w = 1; w < NWAVE; ++w) {
            float4 a = rec[w * QB + t];
            float a1 = a.x, a2 = a.y;
            int ac1 = __float_as_int(a.z), ac2 = __float_as_int(a.w);
            if (a1 > m1)      { m2 = m1; k2 = k1; m1 = a1; k1 = ac1; }
            else if (a1 > m2) { m2 = a1; k2 = ac1; }
            if (a2 > m2)      { m2 = a2; k2 = ac2; }
        }
        int gq = qbase + t;
        if (gq < QT) {
            ((float4*)(ws + WS_REC))[gq * 2 + shalf] =
                make_float4(m1, m2, __int_as_float(k1), __int_as_float(k2));
        }
    }
}

// ---------------------------------------------------------------------------
// Index recovery: ONE WAVE per query. The 64 lanes each rescan one point of
// the tracked 64-point chunk; ballot finds the bit-exact match in one step;
// shfl broadcasts the dot product. 8 queries per 512-thread block.
// Small losses fused in (grid-stride over N).
// ---------------------------------------------------------------------------
__global__ __launch_bounds__(512) void recover_k(
    const float* __restrict__ offq, const float* __restrict__ nearq,
    const float* __restrict__ surf, const float* __restrict__ norms,
    const float* __restrict__ nmpred, const float* __restrict__ nppred,
    const float* __restrict__ mp, const float* __restrict__ mg,
    const float* __restrict__ sn,
    float* __restrict__ ws, int S, int Qoff, int QT, int N)
{
    const int t    = threadIdx.x;
    const int lane = t & 63;
    const int wv   = t >> 6;                       // 0..7
    const int q    = blockIdx.x * 8 + wv;

    float termOri = 0.f, termNori = 0.f;
    if (q < QT) {
        const float4* recs = (const float4*)(ws + WS_REC);
        float4 r0 = recs[q * 2 + 0], r1 = recs[q * 2 + 1];
        float M1 = r0.x, M2 = r0.y;
        int c1 = __float_as_int(r0.z), c2 = __float_as_int(r0.w);
        {
            float a1 = r1.x, a2 = r1.y;
            int ac1 = __float_as_int(r1.z), ac2 = __float_as_int(r1.w);
            if (a1 > M1)      { M2 = M1; c2 = c1; M1 = a1; c1 = ac1; }
            else if (a1 > M2) { M2 = a1; c2 = ac1; }
            if (a2 > M2)      { M2 = a2; c2 = ac2; }
        }
        bool isNear = (q >= Qoff);
        const float* qp = isNear ? (nearq + 3 * (q - Qoff)) : (offq + 3 * q);
        float qx = qp[0], qy = qp[1], qz = qp[2];

        // ---- chunk c1: lane l evaluates point c1*64+l ----
        int j1 = c1 * CHK + lane;
        float g1 = -3.0e38f, dot1 = 0.f;
        if (j1 < S) {
            float sx = surf[3*j1], sy = surf[3*j1+1], sz = surf[3*j1+2];
            g1 = score(qx, qy, qz, sx, sy, sz, neg_half_norm2(sx, sy, sz));
            float nx = norms[3*j1], ny = norms[3*j1+1], nz = norms[3*j1+2];
            dot1 = fmaf(qx - sx, nx, fmaf(qy - sy, ny, (qz - sz) * nz));
        }
        unsigned long long m1mask = __ballot(g1 == M1);
        int I1; float d1;
        if (m1mask) {
            int l1 = __ffsll(m1mask) - 1;
            I1 = c1 * CHK + l1;
            d1 = __shfl(dot1, l1);
        } else {
            I1 = 0;
            d1 = dot_at(surf, norms, 0, qx, qy, qz);
        }

        // ---- chunk c2, excluding I1 ----
        int j2 = c2 * CHK + lane;
        float g2 = -3.0e38f, dot2 = 0.f;
        if (j2 < S) {
            float sx = surf[3*j2], sy = surf[3*j2+1], sz = surf[3*j2+2];
            g2 = score(qx, qy, qz, sx, sy, sz, neg_half_norm2(sx, sy, sz));
            float nx = norms[3*j2], ny = norms[3*j2+1], nz = norms[3*j2+2];
            dot2 = fmaf(qx - sx, nx, fmaf(qy - sy, ny, (qz - sz) * nz));
        }
        unsigned long long m2mask = __ballot(g2 == M2);
        int rel = I1 - c2 * CHK;
        if (rel >= 0 && rel < 64) m2mask &= ~(1ull << rel);
        int I2; float d2;
        if (m2mask) {
            int l2 = __ffsll(m2mask) - 1;
            I2 = c2 * CHK + l2;
            d2 = __shfl(dot2, l2);
        } else {
            I2 = (I1 == 0 && S > 1) ? 1 : 0;
            d2 = dot_at(surf, norms, I2, qx, qy, qz);
        }

        float ms = d1 + d2;                                   // sign(mean)==sign(sum)
        float sgn = (ms > 0.f) ? 1.f : ((ms < 0.f) ? -1.f : 0.f);
        float pred = isNear ? nppred[q - Qoff] : nmpred[q];
        float term = fmaxf(0.f, -pred * sgn);
        if (lane == 0) {
            termOri  = isNear ? 0.f : term;
            termNori = isNear ? term : 0.f;
        }
    }

    // fused prep (small losses), grid-stride over N
    float sdf = 0.f, eik = 0.f, gn = 0.f;
    for (int i = blockIdx.x * 512 + t; i < N; i += gridDim.x * 512) {
        float p = mp[i];
        sdf += p * p;
        float gx = mg[3*i], gy = mg[3*i+1], gz = mg[3*i+2];
        float nrm = sqrtf(fmaf(gx, gx, fmaf(gy, gy, gz * gz)));
        float d = nrm - 1.0f;
        eik += d * d;
        float nx = sn[3*i], ny = sn[3*i+1], nz = sn[3*i+2];
        float dx = gx - nx, dy = gy - ny, dz = gz - nz;
        gn += fmaf(dx, dx, fmaf(dy, dy, dz * dz));
    }

    // wave-level shuffle reduce, then 8-wave LDS combine
    float v0 = termOri, v1 = termNori, v2 = sdf, v3 = eik, v4 = gn;
    #pragma unroll
    for (int off = 32; off > 0; off >>= 1) {
        v0 += __shfl_down(v0, off);
        v1 += __shfl_down(v1, off);
        v2 += __shfl_down(v2, off);
        v3 += __shfl_down(v3, off);
        v4 += __shfl_down(v4, off);
    }
    __shared__ float red[5][NWAVE];
    if (lane == 0) {
        red[0][wv] = v0; red[1][wv] = v1; red[2][wv] = v2;
        red[3][wv] = v3; red[4][wv] = v4;
    }
    __syncthreads();
    if (t == 0) {
        #pragma unroll
        for (int k = 0; k < 5; ++k) {
            float s = 0.f;
            #pragma unroll
            for (int w = 0; w < NWAVE; ++w) s += red[k][w];
            ws[k * WS_STRIDE + blockIdx.x] = s;
        }
    }
}

// ---------------------------------------------------------------------------
__global__ __launch_bounds__(256) void final_k(
    const float* __restrict__ ws, float* __restrict__ out,
    int N, int RB, int Qoff, int Qnear)
{
    __shared__ float r[5][256];
    int t = threadIdx.x;
    float s[5] = {0.f, 0.f, 0.f, 0.f, 0.f};
    for (int i = t; i < RB; i += 256) {
        #pragma unroll
        for (int k = 0; k < 5; ++k) s[k] += ws[k * WS_STRIDE + i];
    }
    #pragma unroll
    for (int k = 0; k < 5; ++k) r[k][t] = s[k];
    __syncthreads();
    for (int off = 128; off > 0; off >>= 1) {
        if (t < off) {
            #pragma unroll
            for (int k = 0; k < 5; ++k) r[k][t] += r[k][t + off];
        }
        __syncthreads();
    }
    if (t == 0) {
        float orim  = r[0][0] / (float)Qoff;
        float norim = r[1][0] / (float)Qnear;
        float sdfm  = r[2][0] / (float)N;
        float eikm  = r[3][0] / (float)N;
        float gnm   = r[4][0] / (3.0f * (float)N);
        out[0] = SDF_W * sdfm + EIK_W * eikm + ORI_W * orim
               + NEAR_ORI_W * norim + GRADN_W * gnm;
        out[1] = sdfm;
        out[2] = eikm;
        out[3] = orim;
        out[4] = norim;
        out[5] = gnm;
    }
}

extern "C" void kernel_launch(void* const* d_in, const int* in_sizes, int n_in,
                              void* d_out, int out_size, void* d_ws, size_t ws_size,
                              hipStream_t stream)
{
    const float* mp    = (const float*)d_in[0];  // manifold_pred      [N,1]
    const float* mg    = (const float*)d_in[1];  // manifold_grad      [N,3]
    const float* nmp   = (const float*)d_in[2];  // nonmanifold_pred   [N,1]
    const float* npp   = (const float*)d_in[3];  // near_points_pred   [N,1]
    const float* sp    = (const float*)d_in[4];  // surface_points     [S,3]
    const float* sn    = (const float*)d_in[5];  // surface_normals    [S,3]
    const float* offp  = (const float*)d_in[6];  // off_surface_points [Q,3]
    const float* nearp = (const float*)d_in[7];  // near_points        [Q,3]
    float* out = (float*)d_out;

    const int N     = in_sizes[0];
    const int S     = in_sizes[4] / 3;
    const int Qoff  = in_sizes[2];
    const int Qnear = in_sizes[3];
    const int QT    = Qoff + Qnear;

    float* ws = (float*)d_ws;

    const int qgroups = (QT + QB - 1) / QB;       // 128 for QT=32768
    const int RB      = (QT + 7) / 8;             // 4096 recover blocks

    nn_scan<<<qgroups * 2, 512, 0, stream>>>(offp, nearp, sp, ws, S, Qoff, QT);
    recover_k<<<RB, 512, 0, stream>>>(offp, nearp, sp, sn, nmp, npp,
                                      mp, mg, sn, ws, S, Qoff, QT, N);
    final_k<<<1, 256, 0, stream>>>(ws, out, N, RB, Qoff, Qnear);
}

// Round 2
// 160.422 us; speedup vs baseline: 1.0600x; 1.0600x over previous
//
#include <hip/hip_runtime.h>
#include <math.h>

#define SDF_W      7000.0f
#define EIK_W      600.0f
#define ORI_W      500.0f
#define NEAR_ORI_W 10.0f
#define GRADN_W    200.0f

#define TILE   2048          // points per LDS tile (32 KB of float4)
#define NWAVE  8             // 512-thread blocks
#define CHK    64            // chunk granularity for index recovery
#define QPL    4             // queries per lane in nn_scan
#define QB     (QPL * 64)    // queries per block = 256
#define NSPLIT 4             // S-range split (grid = qgroups * NSPLIT)
#define WS_STRIDE 8192       // per-array stride (floats) for block partials
#define WS_REC 65536         // float offset of per-query records

// ws float layout:
//   [k*8192 .. k*8192+RB) : recover-block partials, k = 0:ori 1:nori 2:sdf 3:eik 4:gn
//   [65536 ...)           : records, float4 per (query, S-part): {M1, M2, c1, c2}

__device__ __forceinline__ float neg_half_norm2(float sx, float sy, float sz) {
    return -0.5f * fmaf(sx, sx, fmaf(sy, sy, sz * sz));
}
// Deterministic score; must be bit-identical between nn_scan and recover_k.
__device__ __forceinline__ float score(float qx, float qy, float qz,
                                       float sx, float sy, float sz, float nh) {
    return fmaf(qx, sx, fmaf(qy, sy, fmaf(qz, sz, nh)));
}

__device__ __forceinline__ float dot_at(const float* __restrict__ surf,
                                        const float* __restrict__ norms, int j,
                                        float qx, float qy, float qz) {
    float sx = surf[3*j], sy = surf[3*j+1], sz = surf[3*j+2];
    float nx = norms[3*j], ny = norms[3*j+1], nz = norms[3*j+2];
    return fmaf(qx - sx, nx, fmaf(qy - sy, ny, (qz - sz) * nz));
}

// ---------------------------------------------------------------------------
// Hot kernel: top-2 score values per (query, S-part) with chunk ids.
// QPL=4 queries per lane amortize each broadcast ds_read_b128 over 256
// evals/wave; NSPLIT=4 keeps the grid at 512 blocks (2 blocks/CU, 4
// waves/SIMD) so LDS, VALU, and staging latency overlap across waves.
// M2 update via single v_med3_f32: med3(g, M1, M2) == max(M2, min(g, M1)).
// ---------------------------------------------------------------------------
__global__ __launch_bounds__(512) void nn_scan(
    const float* __restrict__ offq, const float* __restrict__ nearq,
    const float* __restrict__ surf,
    float* __restrict__ ws, int S, int Qoff, int QT)
{
    __shared__ float4 tile[TILE];                 // 32 KB; reused for merge recs
    const int t    = threadIdx.x;
    const int lane = t & 63;
    const int wv   = __builtin_amdgcn_readfirstlane(t >> 6);   // 0..7

    const int qgroup = blockIdx.x >> 2;
    const int part   = blockIdx.x & 3;

    // S split into NSPLIT chunk-aligned parts
    const int partLen = (((S + NSPLIT - 1) / NSPLIT) + (CHK - 1)) & ~(CHK - 1);
    int sb = part * partLen;       if (sb > S) sb = S;
    int se = sb + partLen;         if (se > S) se = S;

    // four queries per lane
    const int qbase = qgroup * QB;
    float qx[QPL], qy[QPL], qz[QPL];
    #pragma unroll
    for (int j = 0; j < QPL; ++j) {
        int q = qbase + j * 64 + lane;
        qx[j] = 0.f; qy[j] = 0.f; qz[j] = 0.f;
        if (q < QT) {
            const float* p = (q < Qoff) ? (offq + 3 * q) : (nearq + 3 * (q - Qoff));
            qx[j] = p[0]; qy[j] = p[1]; qz[j] = p[2];
        }
    }

    float M1[QPL], M2[QPL], P1[QPL], P2[QPL];
    int c1[QPL], c2[QPL];
    #pragma unroll
    for (int j = 0; j < QPL; ++j) {
        M1[j] = -3.0e38f; M2[j] = -3.0e38f;
        P1[j] = -3.0e38f; P2[j] = -3.0e38f;
        c1[j] = 0; c2[j] = 0;
    }

    for (int base = sb; base < se; base += TILE) {
        __syncthreads();
        // ---- stage 2048 points (4 per thread) as (x,y,z,-|s|^2/2) ----
        {
            int p0 = base + t * 4;
            if (p0 + 4 <= se) {
                const float4* g4 = (const float4*)(surf + 3 * p0);   // 48B aligned
                float4 r0 = g4[0], r1 = g4[1], r2 = g4[2];
                tile[t*4+0] = make_float4(r0.x, r0.y, r0.z, neg_half_norm2(r0.x, r0.y, r0.z));
                tile[t*4+1] = make_float4(r0.w, r1.x, r1.y, neg_half_norm2(r0.w, r1.x, r1.y));
                tile[t*4+2] = make_float4(r1.z, r1.w, r2.x, neg_half_norm2(r1.z, r1.w, r2.x));
                tile[t*4+3] = make_float4(r2.y, r2.z, r2.w, neg_half_norm2(r2.y, r2.z, r2.w));
            } else {
                #pragma unroll
                for (int k = 0; k < 4; ++k) {
                    int p = p0 + k;
                    if (p < se) {
                        float sx = surf[3*p], sy = surf[3*p+1], sz = surf[3*p+2];
                        tile[t*4+k] = make_float4(sx, sy, sz, neg_half_norm2(sx, sy, sz));
                    } else {
                        tile[t*4+k] = make_float4(0.f, 0.f, 0.f, -3.0e38f);
                    }
                }
            }
        }
        __syncthreads();
        // ---- scan: wave wv covers 256 pts = 4 chunks of 64 ----
        const int lo = wv * (TILE / NWAVE);
        const float4* tp = tile + lo;
        const int ccbase = (base + lo) >> 6;                  // wave-uniform
        #pragma unroll 1
        for (int c4 = 0; c4 < (TILE / NWAVE) / CHK; ++c4) {
            const float4* cp = tp + c4 * CHK;
            #pragma unroll 8
            for (int o = 0; o < CHK; ++o) {
                float4 s4 = cp[o];                            // broadcast b128
                #pragma unroll
                for (int j = 0; j < QPL; ++j) {
                    float g = score(qx[j], qy[j], qz[j], s4.x, s4.y, s4.z, s4.w);
                    M2[j] = __builtin_amdgcn_fmed3f(g, M1[j], M2[j]);  // uses OLD M1
                    M1[j] = fmaxf(M1[j], g);
                }
            }
            int cid = ccbase + c4;
            #pragma unroll
            for (int j = 0; j < QPL; ++j) {
                c1[j] = (M1[j] != P1[j]) ? cid : c1[j];  P1[j] = M1[j];
                c2[j] = (M2[j] != P2[j]) ? cid : c2[j];  P2[j] = M2[j];
            }
        }
    }

    // ---- merge 8 wave-partials per query, write record to ws ----
    __syncthreads();
    float4* rec = tile;                                       // reuse LDS (2048 slots)
    #pragma unroll
    for (int j = 0; j < QPL; ++j)
        rec[wv * QB + j * 64 + lane] =
            make_float4(M1[j], M2[j], __int_as_float(c1[j]), __int_as_float(c2[j]));
    __syncthreads();
    if (t < QB) {
        float4 r = rec[t];
        float m1 = r.x, m2 = r.y;
        int k1 = __float_as_int(r.z), k2 = __float_as_int(r.w);
        #pragma unroll
        for (int w = 1; w < NWAVE; ++w) {
            float4 a = rec[w * QB + t];
            float a1 = a.x, a2 = a.y;
            int ac1 = __float_as_int(a.z), ac2 = __float_as_int(a.w);
            if (a1 > m1)      { m2 = m1; k2 = k1; m1 = a1; k1 = ac1; }
            else if (a1 > m2) { m2 = a1; k2 = ac1; }
            if (a2 > m2)      { m2 = a2; k2 = ac2; }
        }
        int gq = qbase + t;
        if (gq < QT) {
            ((float4*)(ws + WS_REC))[gq * NSPLIT + part] =
                make_float4(m1, m2, __int_as_float(k1), __int_as_float(k2));
        }
    }
}

// ---------------------------------------------------------------------------
// Index recovery: ONE WAVE per query. The 64 lanes each rescan one point of
// the tracked 64-point chunk; ballot finds the bit-exact match in one step;
// shfl broadcasts the pre-computed dot product. 8 queries per 512-thread
// block. Small losses fused in (grid-stride over N).
// ---------------------------------------------------------------------------
__global__ __launch_bounds__(512) void recover_k(
    const float* __restrict__ offq, const float* __restrict__ nearq,
    const float* __restrict__ surf, const float* __restrict__ norms,
    const float* __restrict__ nmpred, const float* __restrict__ nppred,
    const float* __restrict__ mp, const float* __restrict__ mg,
    const float* __restrict__ sn,
    float* __restrict__ ws, int S, int Qoff, int QT, int N)
{
    const int t    = threadIdx.x;
    const int lane = t & 63;
    const int wv   = t >> 6;                       // 0..7
    const int q    = blockIdx.x * 8 + wv;

    float termOri = 0.f, termNori = 0.f;
    if (q < QT) {
        const float4* recs = (const float4*)(ws + WS_REC);
        float M1 = -3.0e38f, M2 = -3.0e38f;
        int c1 = 0, c2 = 0;
        #pragma unroll
        for (int h = 0; h < NSPLIT; ++h) {
            float4 r = recs[q * NSPLIT + h];
            float a1 = r.x, a2 = r.y;
            int ac1 = __float_as_int(r.z), ac2 = __float_as_int(r.w);
            if (a1 > M1)      { M2 = M1; c2 = c1; M1 = a1; c1 = ac1; }
            else if (a1 > M2) { M2 = a1; c2 = ac1; }
            if (a2 > M2)      { M2 = a2; c2 = ac2; }
        }
        bool isNear = (q >= Qoff);
        const float* qp = isNear ? (nearq + 3 * (q - Qoff)) : (offq + 3 * q);
        float qx = qp[0], qy = qp[1], qz = qp[2];

        // ---- chunk c1: lane l evaluates point c1*64+l ----
        int j1 = c1 * CHK + lane;
        float g1 = -3.0e38f, dot1 = 0.f;
        if (j1 < S) {
            float sx = surf[3*j1], sy = surf[3*j1+1], sz = surf[3*j1+2];
            g1 = score(qx, qy, qz, sx, sy, sz, neg_half_norm2(sx, sy, sz));
            float nx = norms[3*j1], ny = norms[3*j1+1], nz = norms[3*j1+2];
            dot1 = fmaf(qx - sx, nx, fmaf(qy - sy, ny, (qz - sz) * nz));
        }
        unsigned long long m1mask = __ballot(g1 == M1);
        int I1; float d1;
        if (m1mask) {
            int l1 = __ffsll(m1mask) - 1;
            I1 = c1 * CHK + l1;
            d1 = __shfl(dot1, l1);
        } else {
            I1 = 0;
            d1 = dot_at(surf, norms, 0, qx, qy, qz);
        }

        // ---- chunk c2, excluding I1 ----
        int j2 = c2 * CHK + lane;
        float g2 = -3.0e38f, dot2 = 0.f;
        if (j2 < S) {
            float sx = surf[3*j2], sy = surf[3*j2+1], sz = surf[3*j2+2];
            g2 = score(qx, qy, qz, sx, sy, sz, neg_half_norm2(sx, sy, sz));
            float nx = norms[3*j2], ny = norms[3*j2+1], nz = norms[3*j2+2];
            dot2 = fmaf(qx - sx, nx, fmaf(qy - sy, ny, (qz - sz) * nz));
        }
        unsigned long long m2mask = __ballot(g2 == M2);
        int rel = I1 - c2 * CHK;
        if (rel >= 0 && rel < 64) m2mask &= ~(1ull << rel);
        int I2; float d2;
        if (m2mask) {
            int l2 = __ffsll(m2mask) - 1;
            I2 = c2 * CHK + l2;
            d2 = __shfl(dot2, l2);
        } else {
            I2 = (I1 == 0 && S > 1) ? 1 : 0;
            d2 = dot_at(surf, norms, I2, qx, qy, qz);
        }

        float ms = d1 + d2;                                   // sign(mean)==sign(sum)
        float sgn = (ms > 0.f) ? 1.f : ((ms < 0.f) ? -1.f : 0.f);
        float pred = isNear ? nppred[q - Qoff] : nmpred[q];
        float term = fmaxf(0.f, -pred * sgn);
        if (lane == 0) {
            termOri  = isNear ? 0.f : term;
            termNori = isNear ? term : 0.f;
        }
    }

    // fused prep (small losses), grid-stride over N
    float sdf = 0.f, eik = 0.f, gn = 0.f;
    for (int i = blockIdx.x * 512 + t; i < N; i += gridDim.x * 512) {
        float p = mp[i];
        sdf += p * p;
        float gx = mg[3*i], gy = mg[3*i+1], gz = mg[3*i+2];
        float nrm = sqrtf(fmaf(gx, gx, fmaf(gy, gy, gz * gz)));
        float d = nrm - 1.0f;
        eik += d * d;
        float nx = sn[3*i], ny = sn[3*i+1], nz = sn[3*i+2];
        float dx = gx - nx, dy = gy - ny, dz = gz - nz;
        gn += fmaf(dx, dx, fmaf(dy, dy, dz * dz));
    }

    // wave-level shuffle reduce, then 8-wave LDS combine
    float v0 = termOri, v1 = termNori, v2 = sdf, v3 = eik, v4 = gn;
    #pragma unroll
    for (int off = 32; off > 0; off >>= 1) {
        v0 += __shfl_down(v0, off);
        v1 += __shfl_down(v1, off);
        v2 += __shfl_down(v2, off);
        v3 += __shfl_down(v3, off);
        v4 += __shfl_down(v4, off);
    }
    __shared__ float red[5][NWAVE];
    if (lane == 0) {
        red[0][wv] = v0; red[1][wv] = v1; red[2][wv] = v2;
        red[3][wv] = v3; red[4][wv] = v4;
    }
    __syncthreads();
    if (t == 0) {
        #pragma unroll
        for (int k = 0; k < 5; ++k) {
            float s = 0.f;
            #pragma unroll
            for (int w = 0; w < NWAVE; ++w) s += red[k][w];
            ws[k * WS_STRIDE + blockIdx.x] = s;
        }
    }
}

// ---------------------------------------------------------------------------
__global__ __launch_bounds__(256) void final_k(
    const float* __restrict__ ws, float* __restrict__ out,
    int N, int RB, int Qoff, int Qnear)
{
    __shared__ float r[5][256];
    int t = threadIdx.x;
    float s[5] = {0.f, 0.f, 0.f, 0.f, 0.f};
    for (int i = t; i < RB; i += 256) {
        #pragma unroll
        for (int k = 0; k < 5; ++k) s[k] += ws[k * WS_STRIDE + i];
    }
    #pragma unroll
    for (int k = 0; k < 5; ++k) r[k][t] = s[k];
    __syncthreads();
    for (int off = 128; off > 0; off >>= 1) {
        if (t < off) {
            #pragma unroll
            for (int k = 0; k < 5; ++k) r[k][t] += r[k][t + off];
        }
        __syncthreads();
    }
    if (t == 0) {
        float orim  = r[0][0] / (float)Qoff;
        float norim = r[1][0] / (float)Qnear;
        float sdfm  = r[2][0] / (float)N;
        float eikm  = r[3][0] / (float)N;
        float gnm   = r[4][0] / (3.0f * (float)N);
        out[0] = SDF_W * sdfm + EIK_W * eikm + ORI_W * orim
               + NEAR_ORI_W * norim + GRADN_W * gnm;
        out[1] = sdfm;
        out[2] = eikm;
        out[3] = orim;
        out[4] = norim;
        out[5] = gnm;
    }
}

extern "C" void kernel_launch(void* const* d_in, const int* in_sizes, int n_in,
                              void* d_out, int out_size, void* d_ws, size_t ws_size,
                              hipStream_t stream)
{
    const float* mp    = (const float*)d_in[0];  // manifold_pred      [N,1]
    const float* mg    = (const float*)d_in[1];  // manifold_grad      [N,3]
    const float* nmp   = (const float*)d_in[2];  // nonmanifold_pred   [N,1]
    const float* npp   = (const float*)d_in[3];  // near_points_pred   [N,1]
    const float* sp    = (const float*)d_in[4];  // surface_points     [S,3]
    const float* sn    = (const float*)d_in[5];  // surface_normals    [S,3]
    const float* offp  = (const float*)d_in[6];  // off_surface_points [Q,3]
    const float* nearp = (const float*)d_in[7];  // near_points        [Q,3]
    float* out = (float*)d_out;

    const int N     = in_sizes[0];
    const int S     = in_sizes[4] / 3;
    const int Qoff  = in_sizes[2];
    const int Qnear = in_sizes[3];
    const int QT    = Qoff + Qnear;

    float* ws = (float*)d_ws;

    const int qgroups = (QT + QB - 1) / QB;       // 128 for QT=32768
    const int RB      = (QT + 7) / 8;             // 4096 recover blocks

    nn_scan<<<qgroups * NSPLIT, 512, 0, stream>>>(offp, nearp, sp, ws, S, Qoff, QT);
    recover_k<<<RB, 512, 0, stream>>>(offp, nearp, sp, sn, nmp, npp,
                                      mp, mg, sn, ws, S, Qoff, QT, N);
    final_k<<<1, 256, 0, stream>>>(ws, out, N, RB, Qoff, Qnear);
}